// Round 8
// baseline (282.424 us; speedup 1.0000x reference)
//
#include <hip/hip_runtime.h>
#include <hip/hip_bf16.h>
#include <math.h>

// ---------- types ----------
typedef __bf16 bf16x8 __attribute__((ext_vector_type(8)));
typedef float  f32x4  __attribute__((ext_vector_type(4)));

#define B_ROWS 8192
#define HSZ    1024

// async global->LDS, 16B per lane. LDS dest must be wave-uniform-base + lane*16.
#define GLOAD16(gsrc, ldst)                                                          \
  __builtin_amdgcn_global_load_lds((const __attribute__((address_space(1))) void*)(gsrc), \
                                   (__attribute__((address_space(3))) void*)(ldst),  \
                                   16, 0, 0)

__device__ inline unsigned short f2bf(float f) {
  union { float f; unsigned u; } x; x.f = f;
  unsigned r = x.u + 0x7fffu + ((x.u >> 16) & 1u);   // RNE
  return (unsigned short)(r >> 16);
}

__device__ inline void store4bf(unsigned short* p, float4 v) {
  ushort4 u;
  u.x = f2bf(v.x); u.y = f2bf(v.y); u.z = f2bf(v.z); u.w = f2bf(v.w);
  *(ushort4*)p = u;  // 8B store
}

__device__ inline float sigm(float x) { return 1.0f / (1.0f + __expf(-x)); }

// ---------- kernel 0: fp32 -> bf16 conversion + T precompute ----------
__global__ void k_convert(const float* __restrict__ inp,   // [8192][1025]
                          const float* __restrict__ h,     // [8192][1024]
                          const float* __restrict__ Wl,    // [4096][2048]
                          const float* __restrict__ Wd,    // [1024][1024]
                          unsigned short* __restrict__ comb, // [8192][2048] bf16 bits (cols 0..1023 = x)
                          unsigned short* __restrict__ Wlb,  // [4096][2048]
                          unsigned short* __restrict__ hb,   // [8192][1024]
                          unsigned short* __restrict__ Wdb,  // [1024][1024]
                          float* __restrict__ Tm1) {         // [8192] = T-1
  const long stride = (long)gridDim.x * blockDim.x;
  const long tid0 = (long)blockIdx.x * blockDim.x + threadIdx.x;

  for (long i = tid0; i < (long)B_ROWS * HSZ / 4; i += stride) {
    float4 v = ((const float4*)h)[i];
    store4bf(hb + i * 4, v);
  }
  for (long i = tid0; i < (long)B_ROWS * HSZ / 4; i += stride) {
    long e = i * 4; long b = e >> 10; long c = e & 1023;
    float4 v = *(const float4*)(inp + b * 1025 + c);
    store4bf(comb + b * 2048 + c, v);
  }
  for (long i = tid0; i < 4096L * 2048 / 4; i += stride) {
    float4 v = ((const float4*)Wl)[i];
    store4bf(Wlb + i * 4, v);
  }
  for (long i = tid0; i < 1024L * 1024 / 4; i += stride) {
    float4 v = ((const float4*)Wd)[i];
    store4bf(Wdb + i * 4, v);
  }
  for (long i = tid0; i < B_ROWS; i += stride) {
    float dt = inp[i * 1025 + 1024];
    Tm1[i] = 1.0f / logf(dt + 2.7183f) - 1.0f;
  }
}

// ---------- kernel 1: C_ST GEMM (8192x1024x1024) + h_adj epilogue (known-good) ----------
__global__ void k_gemm1(const unsigned short* __restrict__ A,   // hb  [8192][1024]
                        const unsigned short* __restrict__ Bm,  // Wdb [1024][1024]
                        const float* __restrict__ h,            // h_cur f32
                        const float* __restrict__ bd,           // b_desc [1024]
                        const float* __restrict__ Tm1,
                        unsigned short* __restrict__ comb) {
  const int K = 1024;
  __shared__ __align__(16) unsigned short As[128 * 32];
  __shared__ __align__(16) unsigned short Bs[128 * 32];
  const int tid = threadIdx.x;
  const int lane = tid & 63;
  const int wave = tid >> 6;
  const int wr = wave >> 1, wc = wave & 1;
  const int bRow = blockIdx.x;    // 0..63
  const int bCol = blockIdx.y;    // 0..7

  const int sRow = tid >> 2;
  const int sK = (tid & 3) * 8;
  const unsigned short* aSrc0 = A + (long)(bRow * 128 + sRow) * K + sK;
  const unsigned short* aSrc1 = A + (long)(bRow * 128 + 64 + sRow) * K + sK;
  const unsigned short* bSrc0 = Bm + (long)(bCol * 128 + sRow) * K + sK;
  const unsigned short* bSrc1 = Bm + (long)(bCol * 128 + 64 + sRow) * K + sK;
  unsigned short* aDst0 = As + tid * 8;
  unsigned short* aDst1 = As + 2048 + tid * 8;
  unsigned short* bDst0 = Bs + tid * 8;
  unsigned short* bDst1 = Bs + 2048 + tid * 8;

  f32x4 acc[4][4] = {};
  const int fr = lane & 15, fk = (lane >> 4) * 8;

  for (int k0 = 0; k0 < K; k0 += 32) {
    GLOAD16(aSrc0 + k0, aDst0);
    GLOAD16(aSrc1 + k0, aDst1);
    GLOAD16(bSrc0 + k0, bDst0);
    GLOAD16(bSrc1 + k0, bDst1);
    __syncthreads();
    bf16x8 a[4], b[4];
#pragma unroll
    for (int m = 0; m < 4; m++) a[m] = *(const bf16x8*)(As + (wr * 64 + m * 16 + fr) * 32 + fk);
#pragma unroll
    for (int n = 0; n < 4; n++) b[n] = *(const bf16x8*)(Bs + (wc * 64 + n * 16 + fr) * 32 + fk);
#pragma unroll
    for (int m = 0; m < 4; m++)
#pragma unroll
      for (int n = 0; n < 4; n++)
        acc[m][n] = __builtin_amdgcn_mfma_f32_16x16x32_bf16(a[m], b[n], acc[m][n], 0, 0, 0);
    __syncthreads();
  }

  const int cr = (lane >> 4) * 4;
  const int cc = lane & 15;
#pragma unroll
  for (int m = 0; m < 4; m++)
#pragma unroll
    for (int n = 0; n < 4; n++) {
      const int col = bCol * 128 + wc * 64 + n * 16 + cc;
#pragma unroll
      for (int r = 0; r < 4; r++) {
        const int row = bRow * 128 + wr * 64 + m * 16 + cr + r;
        float v = acc[m][n][r] + bd[col];
        float cst = tanhf(v);
        float hadj = h[(long)row * HSZ + col] + Tm1[row] * cst;
        comb[(long)row * 2048 + 1024 + col] = f2bf(hadj);
      }
    }
}

// ---------- kernel 2: gates GEMM — B direct-from-L2 to regs, A ring-3 LDS ----------
// BM=256, BN=256(gates), BK=64. 8 waves (2Mx4N), per-wave 128x64.
// B never staged: col-major XCD map keeps each XCD's 2 B-panels (2MB) L2-resident;
// waves load B frags global->reg with one-tile ping-pong prefetch.
// A: ring-3 LDS (3x32KB), 2-tile gload_lds lookahead, swizzled source / swizzled read.
// Sync per K-tile: 1 lgkmcnt(0) + 1 vmcnt(4) + 1 s_barrier. Issue order B(t+1), A(t+2)
// makes the FIFO ledger: top-of-tile queue = [A(t),B(t),A(t+1)] -> vmcnt(4) publishes t.
#define NKT3 32   // 2048/64
__global__ __launch_bounds__(512, 2)
void k_gemm2_bd(const unsigned short* __restrict__ A,   // comb [8192][2048]
                const unsigned short* __restrict__ Bm,  // Wlb  [4096][2048]
                const float* __restrict__ bl,           // b_layers [4096]
                const float* __restrict__ c_cur,        // f32 [8192][1024]
                float* __restrict__ out) {              // h_next | c_next (f32)
  __shared__ __align__(16) unsigned short ldsA[3][16384];   // 3 x 32KB A-tiles [256][64]

  const int tid = threadIdx.x;
  const int lane = tid & 63;
  const int wid = tid >> 6;
  const int wr = wid >> 2;          // 0..1 : row half (128 rows)
  const int wc = wid & 3;           // 0..3 : j-col quarter (16 j x 4 gates)

  // col-major XCD mapping: XCD x owns bCol in {2x, 2x+1} (B L2-resident), all bRows.
  const int bid = blockIdx.x;
  const int xcd = bid & 7;
  const int ii = bid >> 3;                // 0..63
  const int bCol = xcd * 2 + (ii & 1);    // 0..15
  const int bRow = ii >> 1;               // 0..31

  // ---- A staging (pre-swizzled global source; LDS dest linear) ----
  const int strow = tid >> 3;                          // 0..63
  const int gkswz = ((tid & 7) ^ (strow & 7)) << 3;    // swizzled k-chunk
  const unsigned short* aS0 = A + (long)(bRow * 256 +   0 + strow) * 2048 + gkswz;
  const unsigned short* aS1 = A + (long)(bRow * 256 +  64 + strow) * 2048 + gkswz;
  const unsigned short* aS2 = A + (long)(bRow * 256 + 128 + strow) * 2048 + gkswz;
  const unsigned short* aS3 = A + (long)(bRow * 256 + 192 + strow) * 2048 + gkswz;
#define STG_A(bb, kt) {                                   \
    GLOAD16(aS0 + (long)(kt) * 64, &ldsA[bb][    0 + tid * 8]); \
    GLOAD16(aS1 + (long)(kt) * 64, &ldsA[bb][ 4096 + tid * 8]); \
    GLOAD16(aS2 + (long)(kt) * 64, &ldsA[bb][ 8192 + tid * 8]); \
    GLOAD16(aS3 + (long)(kt) * 64, &ldsA[bb][12288 + tid * 8]); }

  // ---- B direct per-lane bases: gate g, W-row g*1024 + bCol*64 + wc*16 + fr ----
  const int fr = lane & 15, q = lane >> 4;
  const unsigned short* bD0 = Bm + (long)(           bCol * 64 + wc * 16 + fr) * 2048 + q * 8;
  const unsigned short* bD1 = Bm + (long)(1024 +     bCol * 64 + wc * 16 + fr) * 2048 + q * 8;
  const unsigned short* bD2 = Bm + (long)(2048 +     bCol * 64 + wc * 16 + fr) * 2048 + q * 8;
  const unsigned short* bD3 = Bm + (long)(3072 +     bCol * 64 + wc * 16 + fr) * 2048 + q * 8;
#define LOADB(dst, kt) {                                         \
    dst[0][0] = *(const bf16x8*)(bD0 + (long)(kt) * 64);         \
    dst[0][1] = *(const bf16x8*)(bD0 + (long)(kt) * 64 + 32);    \
    dst[1][0] = *(const bf16x8*)(bD1 + (long)(kt) * 64);         \
    dst[1][1] = *(const bf16x8*)(bD1 + (long)(kt) * 64 + 32);    \
    dst[2][0] = *(const bf16x8*)(bD2 + (long)(kt) * 64);         \
    dst[2][1] = *(const bf16x8*)(bD2 + (long)(kt) * 64 + 32);    \
    dst[3][0] = *(const bf16x8*)(bD3 + (long)(kt) * 64);         \
    dst[3][1] = *(const bf16x8*)(bD3 + (long)(kt) * 64 + 32); }

  // ---- A fragment read offsets (swizzled), ushort units ----
  int aoff0[8], aoff1[8];
#pragma unroll
  for (int m = 0; m < 8; m++) {
    const int row = wr * 128 + m * 16 + fr;
    const int base = (row >> 6) * 4096 + (row & 63) * 64;
    aoff0[m] = base + (((q)     ^ (fr & 7)) << 3);   // k-chunk q   (kk=0)
    aoff1[m] = base + (((4 + q) ^ (fr & 7)) << 3);   // k-chunk 4+q (kk=1)
  }

  f32x4 acc[8][4] = {};        // [m][gate]
  bf16x8 bPA[4][2], bPB[4][2]; // ping-pong B frags [gate][kk]

  // ---- prologue: B(0); A(0); A(1)  (issue order defines FIFO ledger) ----
  LOADB(bPA, 0);
  STG_A(0, 0);
  STG_A(1, 1);

#define TILE3(t, cur, nxt) {                                                        \
    asm volatile("s_waitcnt lgkmcnt(0)" ::: "memory");                              \
    if ((t) < NKT3 - 1) { asm volatile("s_waitcnt vmcnt(4)" ::: "memory"); }        \
    else                { asm volatile("s_waitcnt vmcnt(0)" ::: "memory"); }        \
    __builtin_amdgcn_sched_barrier(0);                                              \
    __builtin_amdgcn_s_barrier();                                                   \
    __builtin_amdgcn_sched_barrier(0);                                              \
    if ((t) + 1 < NKT3) LOADB(nxt, (t) + 1);                                        \
    if ((t) + 2 < NKT3) STG_A(((t) + 2) % 3, (t) + 2);                              \
    const unsigned short* buf = ldsA[(t) % 3];                                      \
    __builtin_amdgcn_s_setprio(1);                                                  \
    _Pragma("unroll")                                                               \
    for (int mq = 0; mq < 2; mq++) {                                                \
      bf16x8 aF0[4], aF1[4];                                                        \
      _Pragma("unroll")                                                             \
      for (int m = 0; m < 4; m++) {                                                 \
        aF0[m] = *(const bf16x8*)(buf + aoff0[mq * 4 + m]);                         \
        aF1[m] = *(const bf16x8*)(buf + aoff1[mq * 4 + m]);                         \
      }                                                                             \
      _Pragma("unroll")                                                             \
      for (int m = 0; m < 4; m++)                                                   \
        _Pragma("unroll")                                                           \
        for (int g = 0; g < 4; g++) {                                               \
          acc[mq * 4 + m][g] = __builtin_amdgcn_mfma_f32_16x16x32_bf16(aF0[m], cur[g][0], acc[mq * 4 + m][g], 0, 0, 0); \
          acc[mq * 4 + m][g] = __builtin_amdgcn_mfma_f32_16x16x32_bf16(aF1[m], cur[g][1], acc[mq * 4 + m][g], 0, 0, 0); \
        }                                                                           \
    }                                                                               \
    __builtin_amdgcn_s_setprio(0);                                                  \
  }

  for (int t = 0; t < NKT3; t += 2) {
    TILE3(t,     bPA, bPB);
    TILE3(t + 1, bPB, bPA);
  }
#undef TILE3

  // ---- fused LSTM epilogue ----
  const int cr = (lane >> 4) * 4;
  const int cc = lane & 15;
  const int j = bCol * 64 + wc * 16 + cc;       // 0..1023
#pragma unroll
  for (int m = 0; m < 8; m++) {
#pragma unroll
    for (int r = 0; r < 4; r++) {
      const int row = bRow * 256 + wr * 128 + m * 16 + cr + r;
      float iv = sigm(acc[m][0][r] + bl[j]);
      float fv = sigm(acc[m][1][r] + bl[1024 + j]);
      float ov = sigm(acc[m][2][r] + bl[2048 + j]);
      float gv = tanhf(acc[m][3][r] + bl[3072 + j]);
      float cn = fv * c_cur[(long)row * HSZ + j] + iv * gv;
      float hn = ov * tanhf(cn);
      out[(long)row * HSZ + j] = hn;                         // h_next
      out[(long)B_ROWS * HSZ + (long)row * HSZ + j] = cn;    // c_next
    }
  }
}

// ---------- launch ----------
extern "C" void kernel_launch(void* const* d_in, const int* in_sizes, int n_in,
                              void* d_out, int out_size, void* d_ws, size_t ws_size,
                              hipStream_t stream) {
  const float* inp = (const float*)d_in[0];   // input_tensor [8192][1025]
  const float* h   = (const float*)d_in[1];   // h_cur
  const float* c   = (const float*)d_in[2];   // c_cur
  const float* Wl  = (const float*)d_in[3];   // W_layers [4096][2048]
  const float* bl  = (const float*)d_in[4];   // b_layers [4096]
  const float* Wd  = (const float*)d_in[5];   // W_desc [1024][1024]
  const float* bd  = (const float*)d_in[6];   // b_desc [1024]

  char* ws = (char*)d_ws;
  unsigned short* comb = (unsigned short*)(ws);               // 33,554,432 B
  unsigned short* Wlb  = (unsigned short*)(ws + 33554432);    // 16,777,216 B
  unsigned short* hb   = (unsigned short*)(ws + 50331648);    // 16,777,216 B
  unsigned short* Wdb  = (unsigned short*)(ws + 67108864);    //  2,097,152 B
  float*          Tm1  = (float*)(ws + 69206016);             //     32,768 B
  float*          out  = (float*)d_out;                       // f32 outputs

  hipLaunchKernelGGL(k_convert, dim3(2048), dim3(256), 0, stream,
                     inp, h, Wl, Wd, comb, Wlb, hb, Wdb, Tm1);
  hipLaunchKernelGGL(k_gemm1, dim3(64, 8), dim3(256), 0, stream,
                     hb, Wdb, h, bd, Tm1, comb);
  hipLaunchKernelGGL(k_gemm2_bd, dim3(512), dim3(512), 0, stream,
                     comb, Wlb, bl, c, out);
}